// Round 1
// baseline (115.147 us; speedup 1.0000x reference)
//
#include <hip/hip_runtime.h>
#include <math.h>

#define B_ 64
#define T_ 100
#define N_ 20000
#define NSPLIT 32
#define NCHUNK (N_ / NSPLIT)   // 625
#define K1_THREADS 128

// ws layout:
//   [0, B*T*NSPLIT) floats            : partial min d2
//   next B*T*NSPLIT ints              : partial argmin idx
//   next B floats                     : per-batch partial sums
#define PD2_OFF   0
#define PIDX_OFF  (B_ * T_ * NSPLIT * sizeof(float))
#define PSUM_OFF  (PIDX_OFF + B_ * T_ * NSPLIT * sizeof(int))

// ---------------------------------------------------------------------------
// Kernel 1: per (batch, n-slice) partial argmin over 625 boundary points
// for all T waypoints.
// ---------------------------------------------------------------------------
__global__ __launch_bounds__(K1_THREADS) void k1_partial_argmin(
    const float* __restrict__ poses,      // [B,4,4] row-major
    const float* __restrict__ wpts,       // [B,T,3]
    const float* __restrict__ boundary,   // [4,N] (rows x,y,z,1)
    float* __restrict__ pd2,              // [B*T, NSPLIT]
    int*   __restrict__ pidx)             // [B*T, NSPLIT]
{
    __shared__ float4 pts[NCHUNK];        // (lx, ly, lz, p2) per point

    const int blk  = blockIdx.x;
    const int b    = blk / NSPLIT;
    const int s    = blk % NSPLIT;
    const int base = s * NCHUNK;
    const int tid  = threadIdx.x;

    // Analytic SE(3) inverse: Rinv = R^T, lp = R^T (p - t).
    // Pose pointer is block-uniform -> compiler scalarizes these loads.
    const float* P = poses + b * 16;
    const float R00 = P[0], R01 = P[1], R02 = P[2],  t0 = P[3];
    const float R10 = P[4], R11 = P[5], R12 = P[6],  t1 = P[7];
    const float R20 = P[8], R21 = P[9], R22 = P[10], t2 = P[11];

    // Stage local-frame boundary slice into LDS.
    for (int n = tid; n < NCHUNK; n += K1_THREADS) {
        const float px = boundary[0 * N_ + base + n];
        const float py = boundary[1 * N_ + base + n];
        const float pz = boundary[2 * N_ + base + n];
        const float dx = px - t0, dy = py - t1, dz = pz - t2;
        const float lx = R00 * dx + R10 * dy + R20 * dz;
        const float ly = R01 * dx + R11 * dy + R21 * dz;
        const float lz = R02 * dx + R12 * dy + R22 * dz;
        const float p2 = lx * lx + ly * ly + lz * lz;
        pts[n] = make_float4(lx, ly, lz, p2);
    }
    __syncthreads();

    // One waypoint per thread (lanes >= T_ compute waypoint 0, result dropped).
    const int t = (tid < T_) ? tid : 0;
    const float* W = wpts + (b * T_ + t) * 3;
    const float wx = W[0], wy = W[1], wz = W[2];
    const float w2 = wx * wx + wy * wy + wz * wz;

    float best = 3.4e38f;
    int   bi   = base;
#pragma unroll 4
    for (int n = 0; n < NCHUNK; ++n) {
        const float4 p  = pts[n];                          // broadcast read
        const float cross = wx * p.x + wy * p.y + wz * p.z;
        const float d2 = (w2 + p.w) - 2.0f * cross;        // same formula as ref
        if (d2 < best) { best = d2; bi = base + n; }       // first-occurrence
    }

    if (tid < T_) {
        const int o = (b * T_ + t) * NSPLIT + s;
        pd2[o]  = best;
        pidx[o] = bi;
    }
}

// ---------------------------------------------------------------------------
// Kernel 2: per batch, reduce NSPLIT partials per waypoint, compute
// dots = (w - cp) . cn, ExpRelu, and a per-batch partial sum.
// ---------------------------------------------------------------------------
__global__ __launch_bounds__(128) void k2_epilogue(
    const float* __restrict__ poses,
    const float* __restrict__ wpts,
    const float* __restrict__ boundary,   // [4,N]
    const float* __restrict__ bnorm,      // [3,N]
    const float* __restrict__ pd2,
    const int*   __restrict__ pidx,
    float* __restrict__ psum)             // [B]
{
    const int b   = blockIdx.x;
    const int tid = threadIdx.x;

    float val = 0.0f;
    if (tid < T_) {
        const int i = b * T_ + tid;
        const float* d2p = pd2  + i * NSPLIT;
        const int*   ixp = pidx + i * NSPLIT;
        float best = d2p[0];
        int   bi   = ixp[0];
#pragma unroll
        for (int s2 = 1; s2 < NSPLIT; ++s2) {
            const float d = d2p[s2];
            if (d < best) { best = d; bi = ixp[s2]; }      // lowest idx on tie
        }

        const float* P = poses + b * 16;
        const float R00 = P[0], R01 = P[1], R02 = P[2],  t0 = P[3];
        const float R10 = P[4], R11 = P[5], R12 = P[6],  t1 = P[7];
        const float R20 = P[8], R21 = P[9], R22 = P[10], t2 = P[11];

        const float px = boundary[0 * N_ + bi];
        const float py = boundary[1 * N_ + bi];
        const float pz = boundary[2 * N_ + bi];
        const float dx = px - t0, dy = py - t1, dz = pz - t2;
        const float cpx = R00 * dx + R10 * dy + R20 * dz;
        const float cpy = R01 * dx + R11 * dy + R21 * dz;
        const float cpz = R02 * dx + R12 * dy + R22 * dz;

        const float nx = bnorm[0 * N_ + bi];
        const float ny = bnorm[1 * N_ + bi];
        const float nz = bnorm[2 * N_ + bi];
        const float cnx = R00 * nx + R10 * ny + R20 * nz;
        const float cny = R01 * nx + R11 * ny + R21 * nz;
        const float cnz = R02 * nx + R12 * ny + R22 * nz;

        const float* W = wpts + i * 3;
        const float dots = (W[0] - cpx) * cnx + (W[1] - cpy) * cny + (W[2] - cpz) * cnz;
        // ExpRelu: alpha=1, beta=0.5
        val = (dots > 0.0f) ? (dots + 1.0f) : expf(0.5f * dots);
    }

    __shared__ float red[128];
    red[tid] = val;
    __syncthreads();
    for (int s2 = 64; s2 > 0; s2 >>= 1) {
        if (tid < s2) red[tid] += red[tid + s2];
        __syncthreads();
    }
    if (tid == 0) psum[b] = red[0];
}

// ---------------------------------------------------------------------------
// Kernel 3: final mean over B partial sums.
// ---------------------------------------------------------------------------
__global__ __launch_bounds__(64) void k3_final(
    const float* __restrict__ psum,       // [B]
    float* __restrict__ out)
{
    const int tid = threadIdx.x;
    float v = (tid < B_) ? psum[tid] : 0.0f;
#pragma unroll
    for (int off = 32; off > 0; off >>= 1)
        v += __shfl_down(v, off, 64);
    if (tid == 0) out[0] = v / (float)(B_ * T_);
}

extern "C" void kernel_launch(void* const* d_in, const int* in_sizes, int n_in,
                              void* d_out, int out_size, void* d_ws, size_t ws_size,
                              hipStream_t stream) {
    const float* poses    = (const float*)d_in[0];
    const float* wpts     = (const float*)d_in[1];
    const float* boundary = (const float*)d_in[2];
    const float* bnorm    = (const float*)d_in[3];
    float* out = (float*)d_out;

    float* pd2  = (float*)((char*)d_ws + PD2_OFF);
    int*   pidx = (int*)  ((char*)d_ws + PIDX_OFF);
    float* psum = (float*)((char*)d_ws + PSUM_OFF);

    k1_partial_argmin<<<B_ * NSPLIT, K1_THREADS, 0, stream>>>(
        poses, wpts, boundary, pd2, pidx);
    k2_epilogue<<<B_, 128, 0, stream>>>(
        poses, wpts, boundary, bnorm, pd2, pidx, psum);
    k3_final<<<1, 64, 0, stream>>>(psum, out);
}

// Round 2
// 92.986 us; speedup vs baseline: 1.2383x; 1.2383x over previous
//
#include <hip/hip_runtime.h>
#include <math.h>
#include <float.h>

#define B_ 64
#define T_ 100
#define N_ 20000
#define NQ_TOTAL (B_ * T_)        // 6400 queries
#define NCHUNKS 40
#define CHUNK (N_ / NCHUNKS)      // 500 points per chunk
#define PAIRS (CHUNK / 2)         // 250
#define GROUPS (PAIRS / 2)        // 125 (4 points per group)
#define QG 256                    // queries per block
#define NQG (NQ_TOTAL / QG)       // 25
#define K1_THREADS 128            // 2 queries per thread

typedef float f2 __attribute__((ext_vector_type(2)));
typedef float f4 __attribute__((ext_vector_type(4)));

// ws layout: pd2 float[NCHUNKS*NQ_TOTAL] (1.024 MB) then pidx u16 (0.512 MB)
#define PD2_OFF  0
#define PIDX_OFF (NCHUNKS * NQ_TOTAL * sizeof(float))

// ---------------------------------------------------------------------------
// Kernel 1: global-frame partial 1-NN. Block = (query-group, chunk).
// Each thread owns 2 queries; chunk staged in LDS as (-2g, |g|^2) pairs.
// ---------------------------------------------------------------------------
__global__ __launch_bounds__(K1_THREADS) void k1_nn(
    const float* __restrict__ poses,      // [B,4,4]
    const float* __restrict__ wpts,       // [B,T,3]
    const float* __restrict__ boundary,   // [4,N]
    float* __restrict__ pd2,              // [NCHUNKS][NQ_TOTAL]
    unsigned short* __restrict__ pidx,    // [NCHUNKS][NQ_TOTAL]
    float* __restrict__ out)
{
    __shared__ f4 sh[PAIRS][2];           // [p][0]={-2x0,-2x1,-2y0,-2y1}
                                          // [p][1]={-2z0,-2z1, p2_0, p2_1}
    const int bx  = blockIdx.x;
    const int qg  = bx / NCHUNKS;
    const int c   = bx - qg * NCHUNKS;
    const int base = c * CHUNK;
    const int tid = threadIdx.x;

    if (bx == 0 && tid == 0) out[0] = 0.0f;   // k2 accumulates atomically

    // ---- stage chunk (global frame, batch-independent) ----
    for (int p = tid; p < PAIRS; p += K1_THREADS) {
        const int n0 = base + 2 * p;
        const float x0 = boundary[n0],          x1 = boundary[n0 + 1];
        const float y0 = boundary[N_ + n0],     y1 = boundary[N_ + n0 + 1];
        const float z0 = boundary[2 * N_ + n0], z1 = boundary[2 * N_ + n0 + 1];
        f4 a = { -2.f * x0, -2.f * x1, -2.f * y0, -2.f * y1 };
        f4 b = { -2.f * z0, -2.f * z1,
                 x0 * x0 + y0 * y0 + z0 * z0,
                 x1 * x1 + y1 * y1 + z1 * z1 };
        sh[p][0] = a;
        sh[p][1] = b;
    }

    // ---- per-thread queries: global waypoint q = R w + t ----
    const int i0 = qg * QG + tid;
    const int i1 = i0 + K1_THREADS;

    float q0x, q0y, q0z, q1x, q1y, q1z;
    {
        int b0 = i0 / T_;
        const float* P = poses + b0 * 16;
        const float* W = wpts + i0 * 3;
        float wx = W[0], wy = W[1], wz = W[2];
        q0x = P[0] * wx + P[1] * wy + P[2]  * wz + P[3];
        q0y = P[4] * wx + P[5] * wy + P[6]  * wz + P[7];
        q0z = P[8] * wx + P[9] * wy + P[10] * wz + P[11];
    }
    {
        int b1 = i1 / T_;
        const float* P = poses + b1 * 16;
        const float* W = wpts + i1 * 3;
        float wx = W[0], wy = W[1], wz = W[2];
        q1x = P[0] * wx + P[1] * wy + P[2]  * wz + P[3];
        q1y = P[4] * wx + P[5] * wy + P[6]  * wz + P[7];
        q1z = P[8] * wx + P[9] * wy + P[10] * wz + P[11];
    }
    __syncthreads();

    const f2 v0x = { q0x, q0x }, v0y = { q0y, q0y }, v0z = { q0z, q0z };
    const f2 v1x = { q1x, q1x }, v1y = { q1y, q1y }, v1z = { q1z, q1z };

    float best0 = FLT_MAX, best1 = FLT_MAX;
    int   bg0 = 0, bg1 = 0;

#pragma unroll 5
    for (int g = 0; g < GROUPS; ++g) {
        const f4 a0 = sh[2 * g][0],     b0 = sh[2 * g][1];
        const f4 a1 = sh[2 * g + 1][0], b1 = sh[2 * g + 1][1];
        const f2 mx0 = { a0.x, a0.y }, my0 = { a0.z, a0.w };
        const f2 mz0 = { b0.x, b0.y }, p20 = { b0.z, b0.w };
        const f2 mx1 = { a1.x, a1.y }, my1 = { a1.z, a1.w };
        const f2 mz1 = { b1.x, b1.y }, p21 = { b1.z, b1.w };

        // query 0: e = p2 - 2 q.g  (3 packed FMAs per 2 points)
        f2 eA = __builtin_elementwise_fma(mx0, v0x,
                __builtin_elementwise_fma(my0, v0y,
                __builtin_elementwise_fma(mz0, v0z, p20)));
        f2 eB = __builtin_elementwise_fma(mx1, v0x,
                __builtin_elementwise_fma(my1, v0y,
                __builtin_elementwise_fma(mz1, v0z, p21)));
        float m0 = fminf(fminf(eA.x, eA.y), fminf(eB.x, eB.y));
        if (m0 < best0) { best0 = m0; bg0 = g; }

        // query 1
        f2 eC = __builtin_elementwise_fma(mx0, v1x,
                __builtin_elementwise_fma(my0, v1y,
                __builtin_elementwise_fma(mz0, v1z, p20)));
        f2 eD = __builtin_elementwise_fma(mx1, v1x,
                __builtin_elementwise_fma(my1, v1y,
                __builtin_elementwise_fma(mz1, v1z, p21)));
        float m1 = fminf(fminf(eC.x, eC.y), fminf(eD.x, eD.y));
        if (m1 < best1) { best1 = m1; bg1 = g; }
    }

    // ---- resolve exact index inside winning group (identical FMA math) ----
    {
        const f4 a0 = sh[2 * bg0][0],     b0 = sh[2 * bg0][1];
        const f4 a1 = sh[2 * bg0 + 1][0], b1 = sh[2 * bg0 + 1][1];
        const f2 mx0 = { a0.x, a0.y }, my0 = { a0.z, a0.w };
        const f2 mz0 = { b0.x, b0.y }, p20 = { b0.z, b0.w };
        const f2 mx1 = { a1.x, a1.y }, my1 = { a1.z, a1.w };
        const f2 mz1 = { b1.x, b1.y }, p21 = { b1.z, b1.w };
        f2 eA = __builtin_elementwise_fma(mx0, v0x,
                __builtin_elementwise_fma(my0, v0y,
                __builtin_elementwise_fma(mz0, v0z, p20)));
        f2 eB = __builtin_elementwise_fma(mx1, v0x,
                __builtin_elementwise_fma(my1, v0y,
                __builtin_elementwise_fma(mz1, v0z, p21)));
        int loc = 4 * bg0;
        int li = (eA.x == best0) ? loc
               : (eA.y == best0) ? loc + 1
               : (eB.x == best0) ? loc + 2 : loc + 3;
        const int o = c * NQ_TOTAL + i0;
        pd2[o]  = best0;
        pidx[o] = (unsigned short)(base + li);
    }
    {
        const f4 a0 = sh[2 * bg1][0],     b0 = sh[2 * bg1][1];
        const f4 a1 = sh[2 * bg1 + 1][0], b1 = sh[2 * bg1 + 1][1];
        const f2 mx0 = { a0.x, a0.y }, my0 = { a0.z, a0.w };
        const f2 mz0 = { b0.x, b0.y }, p20 = { b0.z, b0.w };
        const f2 mx1 = { a1.x, a1.y }, my1 = { a1.z, a1.w };
        const f2 mz1 = { b1.x, b1.y }, p21 = { b1.z, b1.w };
        f2 eC = __builtin_elementwise_fma(mx0, v1x,
                __builtin_elementwise_fma(my0, v1y,
                __builtin_elementwise_fma(mz0, v1z, p20)));
        f2 eD = __builtin_elementwise_fma(mx1, v1x,
                __builtin_elementwise_fma(my1, v1y,
                __builtin_elementwise_fma(mz1, v1z, p21)));
        int loc = 4 * bg1;
        int li = (eC.x == best1) ? loc
               : (eC.y == best1) ? loc + 1
               : (eD.x == best1) ? loc + 2 : loc + 3;
        const int o = c * NQ_TOTAL + i1;
        pd2[o]  = best1;
        pidx[o] = (unsigned short)(base + li);
    }
}

// ---------------------------------------------------------------------------
// Kernel 2: reduce 40 chunk-partials per query, global-frame epilogue,
// block-reduce, atomicAdd into out (zeroed by k1).
// dots = (q - g) . n  (rotation-invariant == reference's local-frame dot)
// ---------------------------------------------------------------------------
__global__ __launch_bounds__(256) void k2_epilogue(
    const float* __restrict__ poses,
    const float* __restrict__ wpts,
    const float* __restrict__ boundary,   // [4,N]
    const float* __restrict__ bnorm,      // [3,N]
    const float* __restrict__ pd2,
    const unsigned short* __restrict__ pidx,
    float* __restrict__ out)
{
    const int tid = threadIdx.x;
    const int i = blockIdx.x * 256 + tid;     // grid = 25 -> i in [0,6400)

    float best = FLT_MAX;
    int bi = 0;
#pragma unroll 8
    for (int c = 0; c < NCHUNKS; ++c) {
        const float d  = pd2[c * NQ_TOTAL + i];
        const int   ix = pidx[c * NQ_TOTAL + i];
        if (d < best) { best = d; bi = ix; }  // lowest chunk wins ties
    }

    const int b = i / T_;
    const float* P = poses + b * 16;
    const float* W = wpts + i * 3;
    const float wx = W[0], wy = W[1], wz = W[2];
    const float qx = P[0] * wx + P[1] * wy + P[2]  * wz + P[3];
    const float qy = P[4] * wx + P[5] * wy + P[6]  * wz + P[7];
    const float qz = P[8] * wx + P[9] * wy + P[10] * wz + P[11];

    const float gx = boundary[bi], gy = boundary[N_ + bi], gz = boundary[2 * N_ + bi];
    const float nx = bnorm[bi],    ny = bnorm[N_ + bi],    nz = bnorm[2 * N_ + bi];

    const float dots = (qx - gx) * nx + (qy - gy) * ny + (qz - gz) * nz;
    // ExpRelu: alpha=1, beta=0.5; scaled for the final mean
    float val = (dots > 0.0f) ? (dots + 1.0f) : expf(0.5f * dots);
    val *= (1.0f / (float)NQ_TOTAL);

    __shared__ float red[256];
    red[tid] = val;
    __syncthreads();
#pragma unroll
    for (int s = 128; s > 0; s >>= 1) {
        if (tid < s) red[tid] += red[tid + s];
        __syncthreads();
    }
    if (tid == 0) atomicAdd(out, red[0]);
}

extern "C" void kernel_launch(void* const* d_in, const int* in_sizes, int n_in,
                              void* d_out, int out_size, void* d_ws, size_t ws_size,
                              hipStream_t stream) {
    const float* poses    = (const float*)d_in[0];
    const float* wpts     = (const float*)d_in[1];
    const float* boundary = (const float*)d_in[2];
    const float* bnorm    = (const float*)d_in[3];
    float* out = (float*)d_out;

    float*          pd2  = (float*)((char*)d_ws + PD2_OFF);
    unsigned short* pidx = (unsigned short*)((char*)d_ws + PIDX_OFF);

    k1_nn<<<NQG * NCHUNKS, K1_THREADS, 0, stream>>>(
        poses, wpts, boundary, pd2, pidx, out);
    k2_epilogue<<<NQ_TOTAL / 256, 256, 0, stream>>>(
        poses, wpts, boundary, bnorm, pd2, pidx, out);
}

// Round 3
// 81.004 us; speedup vs baseline: 1.4215x; 1.1479x over previous
//
#include <hip/hip_runtime.h>
#include <math.h>
#include <float.h>

#define B_ 64
#define T_ 100
#define N_ 20000
#define NQ (B_ * T_)              // 6400 queries
#define NCHUNKS 100
#define CHUNK (N_ / NCHUNKS)      // 200 points per chunk
#define PAIRS (CHUNK / 2)         // 100
#define GROUPS (PAIRS / 2)        // 50 (4 points per group)
#define QG 256                    // queries per block
#define NQG (NQ / QG)             // 25
#define K1_THREADS 128            // 2 queries per thread

typedef float f2 __attribute__((ext_vector_type(2)));
typedef float f4 __attribute__((ext_vector_type(4)));
typedef unsigned long long u64;

// ws layout: keys u64[NQ] (51.2 KB). Min over chunks via atomicMin on
// packed key = (sortable(e) << 32) | point_idx  -> min e, ties -> lowest idx.
#define KEYS_OFF 0

// Map f32 -> u32 preserving < order for all finite values (incl. negatives).
__device__ __forceinline__ unsigned int f32_sortable(float f) {
    unsigned int u = __float_as_uint(f);
    return ((int)u >= 0) ? (u | 0x80000000u) : ~u;
}

// ---------------------------------------------------------------------------
// Kernel 0: init keys to +inf-equivalent, zero the output accumulator.
// ---------------------------------------------------------------------------
__global__ __launch_bounds__(256) void k0_init(u64* __restrict__ keys,
                                               float* __restrict__ out)
{
    const int i = blockIdx.x * 256 + threadIdx.x;
    keys[i] = ~0ull;
    if (i == 0) out[0] = 0.0f;
}

// ---------------------------------------------------------------------------
// Kernel 1: global-frame partial 1-NN. Block = (query-group, chunk).
// Rigid transforms preserve distance: |w - R^T(g-t)| = |(Rw+t) - g|, so the
// NN search runs in the global frame with batch-independent point data.
// Each thread owns 2 queries; chunk staged in LDS as (-2g, |g|^2) pairs.
// Result lands via one u64 atomicMin per (query, chunk).
// ---------------------------------------------------------------------------
__global__ __launch_bounds__(K1_THREADS) void k1_nn(
    const float* __restrict__ poses,      // [B,4,4]
    const float* __restrict__ wpts,       // [B,T,3]
    const float* __restrict__ boundary,   // [4,N]
    u64* __restrict__ keys)               // [NQ]
{
    __shared__ f4 sh[PAIRS][2];           // [p][0]={-2x0,-2x1,-2y0,-2y1}
                                          // [p][1]={-2z0,-2z1, p2_0, p2_1}
    const int bx   = blockIdx.x;
    const int qg   = bx / NCHUNKS;
    const int c    = bx - qg * NCHUNKS;
    const int base = c * CHUNK;
    const int tid  = threadIdx.x;

    // ---- stage chunk (global frame, batch-independent) ----
    if (tid < PAIRS) {
        const int p  = tid;
        const int n0 = base + 2 * p;
        const float x0 = boundary[n0],          x1 = boundary[n0 + 1];
        const float y0 = boundary[N_ + n0],     y1 = boundary[N_ + n0 + 1];
        const float z0 = boundary[2 * N_ + n0], z1 = boundary[2 * N_ + n0 + 1];
        f4 a = { -2.f * x0, -2.f * x1, -2.f * y0, -2.f * y1 };
        f4 b = { -2.f * z0, -2.f * z1,
                 x0 * x0 + y0 * y0 + z0 * z0,
                 x1 * x1 + y1 * y1 + z1 * z1 };
        sh[p][0] = a;
        sh[p][1] = b;
    }

    // ---- per-thread queries: global waypoint q = R w + t ----
    const int i0 = qg * QG + tid;
    const int i1 = i0 + K1_THREADS;

    float q0x, q0y, q0z, q1x, q1y, q1z;
    {
        int b0 = i0 / T_;
        const float* P = poses + b0 * 16;
        const float* W = wpts + i0 * 3;
        float wx = W[0], wy = W[1], wz = W[2];
        q0x = P[0] * wx + P[1] * wy + P[2]  * wz + P[3];
        q0y = P[4] * wx + P[5] * wy + P[6]  * wz + P[7];
        q0z = P[8] * wx + P[9] * wy + P[10] * wz + P[11];
    }
    {
        int b1 = i1 / T_;
        const float* P = poses + b1 * 16;
        const float* W = wpts + i1 * 3;
        float wx = W[0], wy = W[1], wz = W[2];
        q1x = P[0] * wx + P[1] * wy + P[2]  * wz + P[3];
        q1y = P[4] * wx + P[5] * wy + P[6]  * wz + P[7];
        q1z = P[8] * wx + P[9] * wy + P[10] * wz + P[11];
    }
    __syncthreads();

    const f2 v0x = { q0x, q0x }, v0y = { q0y, q0y }, v0z = { q0z, q0z };
    const f2 v1x = { q1x, q1x }, v1y = { q1y, q1y }, v1z = { q1z, q1z };

    float best0 = FLT_MAX, best1 = FLT_MAX;
    int   bg0 = 0, bg1 = 0;

#pragma unroll 5
    for (int g = 0; g < GROUPS; ++g) {
        const f4 a0 = sh[2 * g][0],     b0 = sh[2 * g][1];
        const f4 a1 = sh[2 * g + 1][0], b1 = sh[2 * g + 1][1];
        const f2 mx0 = { a0.x, a0.y }, my0 = { a0.z, a0.w };
        const f2 mz0 = { b0.x, b0.y }, p20 = { b0.z, b0.w };
        const f2 mx1 = { a1.x, a1.y }, my1 = { a1.z, a1.w };
        const f2 mz1 = { b1.x, b1.y }, p21 = { b1.z, b1.w };

        // e = p2 - 2 q.g  (3 packed FMAs per 2 points)
        f2 eA = __builtin_elementwise_fma(mx0, v0x,
                __builtin_elementwise_fma(my0, v0y,
                __builtin_elementwise_fma(mz0, v0z, p20)));
        f2 eB = __builtin_elementwise_fma(mx1, v0x,
                __builtin_elementwise_fma(my1, v0y,
                __builtin_elementwise_fma(mz1, v0z, p21)));
        float m0 = fminf(fminf(eA.x, eA.y), fminf(eB.x, eB.y));
        if (m0 < best0) { best0 = m0; bg0 = g; }

        f2 eC = __builtin_elementwise_fma(mx0, v1x,
                __builtin_elementwise_fma(my0, v1y,
                __builtin_elementwise_fma(mz0, v1z, p20)));
        f2 eD = __builtin_elementwise_fma(mx1, v1x,
                __builtin_elementwise_fma(my1, v1y,
                __builtin_elementwise_fma(mz1, v1z, p21)));
        float m1 = fminf(fminf(eC.x, eC.y), fminf(eD.x, eD.y));
        if (m1 < best1) { best1 = m1; bg1 = g; }
    }

    // ---- resolve exact index inside winning group (identical FMA math) ----
    {
        const f4 a0 = sh[2 * bg0][0],     b0 = sh[2 * bg0][1];
        const f4 a1 = sh[2 * bg0 + 1][0], b1 = sh[2 * bg0 + 1][1];
        const f2 mx0 = { a0.x, a0.y }, my0 = { a0.z, a0.w };
        const f2 mz0 = { b0.x, b0.y }, p20 = { b0.z, b0.w };
        const f2 mx1 = { a1.x, a1.y }, my1 = { a1.z, a1.w };
        const f2 mz1 = { b1.x, b1.y }, p21 = { b1.z, b1.w };
        f2 eA = __builtin_elementwise_fma(mx0, v0x,
                __builtin_elementwise_fma(my0, v0y,
                __builtin_elementwise_fma(mz0, v0z, p20)));
        f2 eB = __builtin_elementwise_fma(mx1, v0x,
                __builtin_elementwise_fma(my1, v0y,
                __builtin_elementwise_fma(mz1, v0z, p21)));
        int loc = 4 * bg0;
        int li = (eA.x == best0) ? loc
               : (eA.y == best0) ? loc + 1
               : (eB.x == best0) ? loc + 2 : loc + 3;
        u64 key = ((u64)f32_sortable(best0) << 32) | (unsigned)(base + li);
        atomicMin(&keys[i0], key);
    }
    {
        const f4 a0 = sh[2 * bg1][0],     b0 = sh[2 * bg1][1];
        const f4 a1 = sh[2 * bg1 + 1][0], b1 = sh[2 * bg1 + 1][1];
        const f2 mx0 = { a0.x, a0.y }, my0 = { a0.z, a0.w };
        const f2 mz0 = { b0.x, b0.y }, p20 = { b0.z, b0.w };
        const f2 mx1 = { a1.x, a1.y }, my1 = { a1.z, a1.w };
        const f2 mz1 = { b1.x, b1.y }, p21 = { b1.z, b1.w };
        f2 eC = __builtin_elementwise_fma(mx0, v1x,
                __builtin_elementwise_fma(my0, v1y,
                __builtin_elementwise_fma(mz0, v1z, p20)));
        f2 eD = __builtin_elementwise_fma(mx1, v1x,
                __builtin_elementwise_fma(my1, v1y,
                __builtin_elementwise_fma(mz1, v1z, p21)));
        int loc = 4 * bg1;
        int li = (eC.x == best1) ? loc
               : (eC.y == best1) ? loc + 1
               : (eD.x == best1) ? loc + 2 : loc + 3;
        u64 key = ((u64)f32_sortable(best1) << 32) | (unsigned)(base + li);
        atomicMin(&keys[i1], key);
    }
}

// ---------------------------------------------------------------------------
// Kernel 2: per query, unpack winning index, global-frame epilogue:
// dots = (q - g) . n  (rotation-invariant == reference's local-frame dot),
// ExpRelu, block-reduce, atomicAdd into out (zeroed by k0).
// ---------------------------------------------------------------------------
__global__ __launch_bounds__(256) void k2_epilogue(
    const float* __restrict__ poses,
    const float* __restrict__ wpts,
    const float* __restrict__ boundary,   // [4,N]
    const float* __restrict__ bnorm,      // [3,N]
    const u64* __restrict__ keys,
    float* __restrict__ out)
{
    const int tid = threadIdx.x;
    const int i = blockIdx.x * 256 + tid;     // grid = 25 -> i in [0,6400)

    const int bi = (int)(unsigned)(keys[i] & 0xFFFFFFFFull);

    const int b = i / T_;
    const float* P = poses + b * 16;
    const float* W = wpts + i * 3;
    const float wx = W[0], wy = W[1], wz = W[2];
    const float qx = P[0] * wx + P[1] * wy + P[2]  * wz + P[3];
    const float qy = P[4] * wx + P[5] * wy + P[6]  * wz + P[7];
    const float qz = P[8] * wx + P[9] * wy + P[10] * wz + P[11];

    const float gx = boundary[bi], gy = boundary[N_ + bi], gz = boundary[2 * N_ + bi];
    const float nx = bnorm[bi],    ny = bnorm[N_ + bi],    nz = bnorm[2 * N_ + bi];

    const float dots = (qx - gx) * nx + (qy - gy) * ny + (qz - gz) * nz;
    // ExpRelu: alpha=1, beta=0.5; pre-scaled for the final mean
    float val = (dots > 0.0f) ? (dots + 1.0f) : expf(0.5f * dots);
    val *= (1.0f / (float)NQ);

    __shared__ float red[256];
    red[tid] = val;
    __syncthreads();
#pragma unroll
    for (int s = 128; s > 0; s >>= 1) {
        if (tid < s) red[tid] += red[tid + s];
        __syncthreads();
    }
    if (tid == 0) atomicAdd(out, red[0]);
}

extern "C" void kernel_launch(void* const* d_in, const int* in_sizes, int n_in,
                              void* d_out, int out_size, void* d_ws, size_t ws_size,
                              hipStream_t stream) {
    const float* poses    = (const float*)d_in[0];
    const float* wpts     = (const float*)d_in[1];
    const float* boundary = (const float*)d_in[2];
    const float* bnorm    = (const float*)d_in[3];
    float* out = (float*)d_out;

    u64* keys = (u64*)((char*)d_ws + KEYS_OFF);

    k0_init<<<NQ / 256, 256, 0, stream>>>(keys, out);
    k1_nn<<<NQG * NCHUNKS, K1_THREADS, 0, stream>>>(
        poses, wpts, boundary, keys);
    k2_epilogue<<<NQ / 256, 256, 0, stream>>>(
        poses, wpts, boundary, bnorm, keys, out);
}